// Round 8
// baseline (1462.939 us; speedup 1.0000x reference)
//
#include <hip/hip_runtime.h>
#include <hip/hip_bf16.h>

typedef unsigned short u16;
typedef unsigned int u32;
typedef __attribute__((ext_vector_type(8))) short short8;
typedef __attribute__((ext_vector_type(4))) float floatx4;

#define NP 16384
#define FD 64
#define FLT_BIG 3.0e38f

#if defined(__has_builtin)
#if __has_builtin(__builtin_amdgcn_fdot2_f32_bf16)
#define HAVE_DOT2 1
#endif
#endif

__device__ __forceinline__ float blo(u32 u) {
  u32 v = u << 16; float f; __builtin_memcpy(&f, &v, 4); return f;
}
__device__ __forceinline__ float bhi(u32 u) {
  u32 v = u & 0xffff0000u; float f; __builtin_memcpy(&f, &v, 4); return f;
}
__device__ __forceinline__ float bf2f(u16 u) {
  u32 v = ((u32)u) << 16; float f; __builtin_memcpy(&f, &v, 4); return f;
}
__device__ __forceinline__ u16 f2bf(float f) {
  u32 u; __builtin_memcpy(&u, &f, 4);
  u += 0x7fffu + ((u >> 16) & 1u);
  return (u16)(u >> 16);
}

#ifdef HAVE_DOT2
typedef __attribute__((ext_vector_type(2))) __bf16 bf16x2;
__device__ __forceinline__ bf16x2 asbf2(u32 u) {
  bf16x2 r; __builtin_memcpy(&r, &u, 4); return r;
}
#endif

// runtime input-dtype sniff (confirmed fp32 in R4/R5; kept for safety)
__device__ __forceinline__ bool sniff_bf16(const void* xg) {
  const u16* p = (const u16*)xg;
  int bad = 0;
#pragma unroll
  for (int t = 0; t < 32; ++t) {
    int e = (p[2 * t] >> 7) & 0xFF;
    bad += (e < 90 || e > 132) ? 1 : 0;
  }
  return bad <= 3;
}

// insert v (known < d[15]) into ascending-sorted 16-array, stable (earlier wins ties)
__device__ __forceinline__ void insert16(float (&d)[16], int (&id)[16], float v, int j) {
#pragma unroll
  for (int t = 15; t >= 1; --t) {
    float a = d[t-1], b = d[t];
    int   ia = id[t-1], ib = id[t];
    bool sh   = v < a;
    bool here = v < b;
    d[t]  = sh ? a  : (here ? v : b);
    id[t] = sh ? ia : (here ? j : ib);
  }
  bool h0 = v < d[0];
  d[0]  = h0 ? v : d[0];
  id[0] = h0 ? j : id[0];
}

// ============ staging layout ============
// d_ws:   sq[NP] floats (64 KB)
// out record (512 B per point = 128 ints):
//   phase 1 (knn):    8 segments x 16 candidate ids (ints 16*s .. 16*s+15)
//   phase 2 (merge2): final 16 ids at ints [0..15] (after reading all 128)
//   phase 3 (mlp):    final 128 fp32 outputs overwrite the record

// ================= K0: squared norms -> ws =================
template<bool BF>
__device__ __forceinline__ void sq_body(const void* x, float* sqw) {
  int i = blockIdx.x * 256 + threadIdx.x;
  float acc = 0.f;
  if (BF) {
    const uint4* xr = (const uint4*)((const u16*)x + (size_t)i * FD);
#pragma unroll
    for (int u = 0; u < 8; ++u) {
      uint4 t = xr[u];
      float v[8] = {blo(t.x), bhi(t.x), blo(t.y), bhi(t.y),
                    blo(t.z), bhi(t.z), blo(t.w), bhi(t.w)};
#pragma unroll
      for (int j = 0; j < 8; ++j) acc = fmaf(v[j], v[j], acc);
    }
  } else {
    const float4* xr = (const float4*)((const float*)x + (size_t)i * FD);
#pragma unroll
    for (int u = 0; u < 16; ++u) {
      float4 t = xr[u];
      acc = fmaf(t.x, t.x, acc); acc = fmaf(t.y, t.y, acc);
      acc = fmaf(t.z, t.z, acc); acc = fmaf(t.w, t.w, acc);
    }
  }
  sqw[i] = acc;
}
__global__ __launch_bounds__(256) void sq_kernel(const void* x, float* sqw) {
  if (sniff_bf16(x)) sq_body<true>(x, sqw); else sq_body<false>(x, sqw);
}

// ======== K1: kNN partials. grid (256 row-blocks, 8 segs); 64 rows/block ========
// lane = row, wave = 512-col sub-segment (wave-uniform j -> scalar xj/sq loads).
// d' = sqj - 2*dot (sqi dropped: row-constant, ordering-invariant).
// 8 KB LDS merge buffer + VGPR<=64 -> 8 blocks/CU resident at grid 2048.
template<bool BF>
__device__ __forceinline__ void knn_body(const void* x, float* outf,
                                         const float* __restrict__ sqw) {
  __shared__ float2 part[16][4][16];     // 8 KB (16-row chunks)

  int tid = threadIdx.x;
  int q = __builtin_amdgcn_readfirstlane(tid >> 6);   // wave id, provably uniform
  int r = tid & 63;
  int i = blockIdx.x * 64 + r;
  int seg0 = blockIdx.y * 2048;

  u32   xiw[32];   // bf16 path
  float xif[64];   // fp32 path
  if (BF) {
    const uint4* xip = (const uint4*)((const u16*)x + (size_t)i * FD);
#pragma unroll
    for (int u = 0; u < 8; ++u) {
      uint4 t = xip[u];
      xiw[4*u+0] = t.x; xiw[4*u+1] = t.y; xiw[4*u+2] = t.z; xiw[4*u+3] = t.w;
    }
  } else {
    const float4* xip = (const float4*)((const float*)x + (size_t)i * FD);
#pragma unroll
    for (int u = 0; u < 16; ++u) {
      float4 t = xip[u];
      xif[4*u+0] = t.x; xif[4*u+1] = t.y; xif[4*u+2] = t.z; xif[4*u+3] = t.w;
    }
  }

  float d16[16]; int i16[16];
#pragma unroll
  for (int t = 0; t < 16; ++t) { d16[t] = FLT_BIG; i16[t] = 0; }

  int jbase = seg0 + q * 512;
  for (int jj = 0; jj < 512; ++jj) {
    int j = jbase + jj;                                // wave-uniform
    float sqj = sqw[j];                                // uniform -> scalar load
    float a0 = 0.f, a1 = 0.f, a2 = 0.f, a3 = 0.f;
    if (BF) {
      const uint4* xjp = (const uint4*)((const u16*)x + (size_t)j * FD);
#pragma unroll
      for (int u = 0; u < 8; ++u) {
        uint4 t = xjp[u];
#ifdef HAVE_DOT2
        a0 = __builtin_amdgcn_fdot2_f32_bf16(asbf2(xiw[4*u+0]), asbf2(t.x), a0, false);
        a1 = __builtin_amdgcn_fdot2_f32_bf16(asbf2(xiw[4*u+1]), asbf2(t.y), a1, false);
        a2 = __builtin_amdgcn_fdot2_f32_bf16(asbf2(xiw[4*u+2]), asbf2(t.z), a2, false);
        a3 = __builtin_amdgcn_fdot2_f32_bf16(asbf2(xiw[4*u+3]), asbf2(t.w), a3, false);
#else
        a0 = fmaf(blo(xiw[4*u+0]), blo(t.x), a0); a1 = fmaf(bhi(xiw[4*u+0]), bhi(t.x), a1);
        a2 = fmaf(blo(xiw[4*u+1]), blo(t.y), a2); a3 = fmaf(bhi(xiw[4*u+1]), bhi(t.y), a3);
        a0 = fmaf(blo(xiw[4*u+2]), blo(t.z), a0); a1 = fmaf(bhi(xiw[4*u+2]), bhi(t.z), a1);
        a2 = fmaf(blo(xiw[4*u+3]), blo(t.w), a2); a3 = fmaf(bhi(xiw[4*u+3]), bhi(t.w), a3);
#endif
      }
    } else {
      const float4* xjp = (const float4*)((const float*)x + (size_t)j * FD);
#pragma unroll
      for (int u = 0; u < 16; ++u) {
        float4 t = xjp[u];
        a0 = fmaf(xif[4*u+0], t.x, a0);
        a1 = fmaf(xif[4*u+1], t.y, a1);
        a2 = fmaf(xif[4*u+2], t.z, a2);
        a3 = fmaf(xif[4*u+3], t.w, a3);
      }
    }
    float dot = (a0 + a1) + (a2 + a3);
    float d = fmaf(-2.f, dot, sqj);
    if (j == i) d = FLT_BIG;                           // exclude self
    if (d < d16[15]) insert16(d16, i16, d, j);
  }

  // chunked cross-wave merge: 4 chunks of 16 rows through 8 KB LDS
  for (int c = 0; c < 4; ++c) {
    __syncthreads();
    if ((r >> 4) == c) {
      int rr = r & 15;
#pragma unroll
      for (int t = 0; t < 16; ++t)
        part[rr][q][t] = make_float2(d16[t], __int_as_float(i16[t]));
    }
    __syncthreads();
    if (tid < 16) {
      float f16d[16]; int f16i[16];
#pragma unroll
      for (int t = 0; t < 16; ++t) { f16d[t] = FLT_BIG; f16i[t] = 0; }
      for (int q2 = 0; q2 < 4; ++q2)        // wave-major = j-ascending: stable ties
        for (int t = 0; t < 16; ++t) {
          float2 v = part[tid][q2][t];
          if (v.x < f16d[15]) insert16(f16d, f16i, v.x, __float_as_int(v.y));
        }
      // ids only: record int slot [16*seg .. 16*seg+15]
      int* op = (int*)outf + (size_t)(blockIdx.x * 64 + c * 16 + tid) * 128
                + blockIdx.y * 16;
#pragma unroll
      for (int t = 0; t < 16; ++t) op[t] = f16i[t];
    }
  }
}
__global__ __launch_bounds__(256, 4) void knn_kernel(const void* x, float* outf,
                                                     const float* __restrict__ sqw) {
  if (sniff_bf16(x)) knn_body<true>(x, outf, sqw);
  else               knn_body<false>(x, outf, sqw);
}

// ======== K2: exact rescore of 128 candidates -> final 16 ids (ints [0..15]) ========
// wave per row; lane l computes dists of candidates l and l+64; lane 0 does the
// stable top-16 scan in record order (= id-ascending within equal-d groups).
template<bool BF>
__device__ __forceinline__ void merge2_body(const void* x, float* outf,
                                            const float* __restrict__ sqw) {
  __shared__ float2 cd[4][128];   // 4 KB
  int tid = threadIdx.x;
  int w = __builtin_amdgcn_readfirstlane(tid >> 6);
  int l = tid & 63;
  int i = blockIdx.x * 4 + w;
  int* rec = (int*)outf + (size_t)i * 128;

  u32   xiw[32];
  float xif[64];
  if (BF) {
    const uint4* xip = (const uint4*)((const u16*)x + (size_t)i * FD);
#pragma unroll
    for (int u = 0; u < 8; ++u) {
      uint4 t = xip[u];
      xiw[4*u+0] = t.x; xiw[4*u+1] = t.y; xiw[4*u+2] = t.z; xiw[4*u+3] = t.w;
    }
  } else {
    const float4* xip = (const float4*)((const float*)x + (size_t)i * FD);
#pragma unroll
    for (int u = 0; u < 16; ++u) {
      float4 t = xip[u];
      xif[4*u+0] = t.x; xif[4*u+1] = t.y; xif[4*u+2] = t.z; xif[4*u+3] = t.w;
    }
  }

#pragma unroll
  for (int cc = 0; cc < 2; ++cc) {
    int c = cc * 64 + l;
    int id = rec[c] & (NP - 1);
    float a0 = 0.f, a1 = 0.f, a2 = 0.f, a3 = 0.f;
    if (BF) {
      const uint4* xjp = (const uint4*)((const u16*)x + (size_t)id * FD);
#pragma unroll
      for (int u = 0; u < 8; ++u) {
        uint4 t = xjp[u];
#ifdef HAVE_DOT2
        a0 = __builtin_amdgcn_fdot2_f32_bf16(asbf2(xiw[4*u+0]), asbf2(t.x), a0, false);
        a1 = __builtin_amdgcn_fdot2_f32_bf16(asbf2(xiw[4*u+1]), asbf2(t.y), a1, false);
        a2 = __builtin_amdgcn_fdot2_f32_bf16(asbf2(xiw[4*u+2]), asbf2(t.z), a2, false);
        a3 = __builtin_amdgcn_fdot2_f32_bf16(asbf2(xiw[4*u+3]), asbf2(t.w), a3, false);
#else
        a0 = fmaf(blo(xiw[4*u+0]), blo(t.x), a0); a1 = fmaf(bhi(xiw[4*u+0]), bhi(t.x), a1);
        a2 = fmaf(blo(xiw[4*u+1]), blo(t.y), a2); a3 = fmaf(bhi(xiw[4*u+1]), bhi(t.y), a3);
        a0 = fmaf(blo(xiw[4*u+2]), blo(t.z), a0); a1 = fmaf(bhi(xiw[4*u+2]), bhi(t.z), a1);
        a2 = fmaf(blo(xiw[4*u+3]), blo(t.w), a2); a3 = fmaf(bhi(xiw[4*u+3]), bhi(t.w), a3);
#endif
      }
    } else {
      const float4* xjp = (const float4*)((const float*)x + (size_t)id * FD);
#pragma unroll
      for (int u = 0; u < 16; ++u) {
        float4 t = xjp[u];
        a0 = fmaf(xif[4*u+0], t.x, a0);
        a1 = fmaf(xif[4*u+1], t.y, a1);
        a2 = fmaf(xif[4*u+2], t.z, a2);
        a3 = fmaf(xif[4*u+3], t.w, a3);
      }
    }
    float dot = (a0 + a1) + (a2 + a3);
    float d = fmaf(-2.f, dot, sqw[id]);                // same d' formula as knn
    if (id == i) d = FLT_BIG;
    cd[w][c] = make_float2(d, __int_as_float(id));
  }
  __syncthreads();

  if (l == 0) {
    float d16[16]; int i16[16];
#pragma unroll
    for (int t = 0; t < 16; ++t) { d16[t] = FLT_BIG; i16[t] = 0; }
    for (int c = 0; c < 128; ++c) {
      float2 v = cd[w][c];
      if (v.x < d16[15]) insert16(d16, i16, v.x, __float_as_int(v.y));
    }
#pragma unroll
    for (int t = 0; t < 16; ++t) rec[t] = i16[t];
  }
}
__global__ __launch_bounds__(256, 4) void merge2_kernel(const void* x, float* outf,
                                                        const float* __restrict__ sqw) {
  if (sniff_bf16(x)) merge2_body<true>(x, outf, sqw);
  else               merge2_body<false>(x, outf, sqw);
}

// ================= K3: edge MLP + max aggregation (MFMA, bf16 compute) =================
// A-frag 16x16x32: lane holds A[m=l&15][k=(l>>4)*8+j].  C/D: col=l&15, row=(l>>4)*4+reg.
template<bool BF>
__device__ __forceinline__ void mlp_body(
    const void* x, const void* W1, const void* b1,
    const void* W2, const void* b2, float* outf,
    short* w1f, short* w2f, short (*hbuf)[2048]) {
  int tid = threadIdx.x;
  for (int s2 = tid; s2 < 4096; s2 += 256) {
    int which = s2 >> 11, t = s2 & 2047;
    int frag = t >> 6, lane = t & 63;
    int nt = frag >> 2, kk = frag & 3;
    int n  = nt * 16 + (lane & 15);
    int kb = kk * 32 + ((lane >> 4) * 8);
    short8 v;
    if (BF) {
      const u16* W = (const u16*)(which ? W2 : W1);
#pragma unroll
      for (int j = 0; j < 8; ++j) v[j] = (short)W[(size_t)(kb + j) * 128 + n];
    } else {
      const float* W = (const float*)(which ? W2 : W1);
#pragma unroll
      for (int j = 0; j < 8; ++j) v[j] = (short)f2bf(W[(size_t)(kb + j) * 128 + n]);
    }
    *(short8*)((which ? w2f : w1f) + t * 8) = v;
  }
  __syncthreads();

  int l = tid & 63, w = tid >> 6;
  int q = l >> 4, c = l & 15;
  short* hb = hbuf[w];

  float b1v[8], b2v[8];
#pragma unroll
  for (int nt = 0; nt < 8; ++nt) {
    b1v[nt] = BF ? bf2f(((const u16*)b1)[nt * 16 + c]) : ((const float*)b1)[nt * 16 + c];
    b2v[nt] = BF ? bf2f(((const u16*)b2)[nt * 16 + c]) : ((const float*)b2)[nt * 16 + c];
  }

  int wid = blockIdx.x * 4 + w;
  for (int p = wid; p < NP; p += 1024) {
    int nb = ((const int*)outf)[(size_t)p * 128 + c] & (NP - 1);
    short8 a1[4];
    if (BF) {
      const short* xp  = (const short*)x + (size_t)p  * FD;
      const short* xnp = (const short*)x + (size_t)nb * FD;
      a1[0] = *(const short8*)(xp + q * 8);
      a1[1] = *(const short8*)(xp + 32 + q * 8);
#pragma unroll
      for (int kk = 2; kk < 4; ++kk) {
        int kb = (kk - 2) * 32 + q * 8;
        short8 xi8 = *(const short8*)(xp + kb);
        short8 xj8 = *(const short8*)(xnp + kb);
        short8 dfr;
#pragma unroll
        for (int j = 0; j < 8; ++j)
          dfr[j] = (short)f2bf(bf2f((u16)xj8[j]) - bf2f((u16)xi8[j]));
        a1[kk] = dfr;
      }
    } else {
      const float* xp  = (const float*)x + (size_t)p  * FD;
      const float* xnp = (const float*)x + (size_t)nb * FD;
#pragma unroll
      for (int j = 0; j < 8; ++j) {
        float xi0 = xp[q * 8 + j], xi1 = xp[32 + q * 8 + j];
        float xj0 = xnp[q * 8 + j], xj1 = xnp[32 + q * 8 + j];
        a1[0][j] = (short)f2bf(xi0);
        a1[1][j] = (short)f2bf(xi1);
        a1[2][j] = (short)f2bf(xj0 - xi0);
        a1[3][j] = (short)f2bf(xj1 - xi1);
      }
    }

#pragma unroll
    for (int nt = 0; nt < 8; ++nt) {
      floatx4 acc = {0.f, 0.f, 0.f, 0.f};
#pragma unroll
      for (int kk = 0; kk < 4; ++kk) {
        short8 b = *(const short8*)(w1f + ((nt * 4 + kk) * 64 + l) * 8);
        acc = __builtin_amdgcn_mfma_f32_16x16x32_bf16(a1[kk], b, acc, 0, 0, 0);
      }
#pragma unroll
      for (int r = 0; r < 4; ++r) {
        float v = acc[r] + b1v[nt];
        v = v > 0.f ? v : 0.f;
        int row  = q * 4 + r;
        int hcol = nt * 16 + c;
        int eidx = ((hcol >> 5) * 64 + ((hcol >> 3) & 3) * 16 + row) * 8 + (hcol & 7);
        hb[eidx] = (short)f2bf(v);
      }
    }

    short8 a2[4];
#pragma unroll
    for (int kk = 0; kk < 4; ++kk)
      a2[kk] = *(const short8*)(hb + (kk * 64 + l) * 8);
#pragma unroll
    for (int nt = 0; nt < 8; ++nt) {
      floatx4 acc = {0.f, 0.f, 0.f, 0.f};
#pragma unroll
      for (int kk = 0; kk < 4; ++kk) {
        short8 b = *(const short8*)(w2f + ((nt * 4 + kk) * 64 + l) * 8);
        acc = __builtin_amdgcn_mfma_f32_16x16x32_bf16(a2[kk], b, acc, 0, 0, 0);
      }
      float m = fmaxf(fmaxf(acc[0], acc[1]), fmaxf(acc[2], acc[3])) + b2v[nt];
      m = fmaxf(m, __shfl_xor(m, 16, 64));
      m = fmaxf(m, __shfl_xor(m, 32, 64));
      if (q == 0) outf[(size_t)p * 128 + nt * 16 + c] = m;
    }
  }
}
__global__ __launch_bounds__(256) void mlp_kernel(
    const void* x, const void* W1, const void* b1,
    const void* W2, const void* b2, float* outf) {
  __shared__ short w1f[16384];
  __shared__ short w2f[16384];
  __shared__ short hbuf[4][2048];
  if (sniff_bf16(x)) mlp_body<true>(x, W1, b1, W2, b2, outf, w1f, w2f, hbuf);
  else               mlp_body<false>(x, W1, b1, W2, b2, outf, w1f, w2f, hbuf);
}

extern "C" void kernel_launch(void* const* d_in, const int* in_sizes, int n_in,
                              void* d_out, int out_size, void* d_ws, size_t ws_size,
                              hipStream_t stream) {
  const void* x  = d_in[0];
  const void* W1 = d_in[1];
  const void* b1 = d_in[2];
  const void* W2 = d_in[3];
  const void* b2 = d_in[4];
  float* outf = (float*)d_out;
  float* sqw  = (float*)d_ws;          // NP floats = 64 KB

  sq_kernel    <<<dim3(NP / 256),   dim3(256), 0, stream>>>(x, sqw);
  knn_kernel   <<<dim3(NP / 64, 8), dim3(256), 0, stream>>>(x, outf, sqw);
  merge2_kernel<<<dim3(NP / 4),     dim3(256), 0, stream>>>(x, outf, sqw);
  mlp_kernel   <<<dim3(256),        dim3(256), 0, stream>>>(x, W1, b1, W2, b2, outf);
}

// Round 9
// 1371.193 us; speedup vs baseline: 1.0669x; 1.0669x over previous
//
#include <hip/hip_runtime.h>
#include <hip/hip_bf16.h>

typedef unsigned short u16;
typedef unsigned int u32;
typedef __attribute__((ext_vector_type(8))) short short8;
typedef __attribute__((ext_vector_type(4))) float floatx4;
typedef __attribute__((ext_vector_type(2))) float floatx2;

#define NP 16384
#define FD 64
#define FLT_BIG 3.0e38f
#define CB 8                      // candidate buffer depth per lane

#if defined(__has_builtin)
#if __has_builtin(__builtin_amdgcn_fdot2_f32_bf16)
#define HAVE_DOT2 1
#endif
#endif

__device__ __forceinline__ float blo(u32 u) {
  u32 v = u << 16; float f; __builtin_memcpy(&f, &v, 4); return f;
}
__device__ __forceinline__ float bhi(u32 u) {
  u32 v = u & 0xffff0000u; float f; __builtin_memcpy(&f, &v, 4); return f;
}
__device__ __forceinline__ float bf2f(u16 u) {
  u32 v = ((u32)u) << 16; float f; __builtin_memcpy(&f, &v, 4); return f;
}
__device__ __forceinline__ u16 f2bf(float f) {
  u32 u; __builtin_memcpy(&u, &f, 4);
  u += 0x7fffu + ((u >> 16) & 1u);
  return (u16)(u >> 16);
}

#ifdef HAVE_DOT2
typedef __attribute__((ext_vector_type(2))) __bf16 bf16x2;
__device__ __forceinline__ bf16x2 asbf2(u32 u) {
  bf16x2 r; __builtin_memcpy(&r, &u, 4); return r;
}
#endif

__device__ __forceinline__ floatx2 pkfma(floatx2 a, floatx2 b, floatx2 c) {
#if defined(__has_builtin) && __has_builtin(__builtin_elementwise_fma)
  return __builtin_elementwise_fma(a, b, c);   // v_pk_fma_f32
#else
  floatx2 r; r.x = fmaf(a.x, b.x, c.x); r.y = fmaf(a.y, b.y, c.y); return r;
#endif
}

// runtime input-dtype sniff (confirmed fp32 in R4/R5; kept for safety)
__device__ __forceinline__ bool sniff_bf16(const void* xg) {
  const u16* p = (const u16*)xg;
  int bad = 0;
#pragma unroll
  for (int t = 0; t < 32; ++t) {
    int e = (p[2 * t] >> 7) & 0xFF;
    bad += (e < 90 || e > 132) ? 1 : 0;
  }
  return bad <= 3;
}

// insert v (known < d[15]) into ascending-sorted 16-array, stable (earlier wins ties)
__device__ __forceinline__ void insert16(float (&d)[16], int (&id)[16], float v, int j) {
#pragma unroll
  for (int t = 15; t >= 1; --t) {
    float a = d[t-1], b = d[t];
    int   ia = id[t-1], ib = id[t];
    bool sh   = v < a;
    bool here = v < b;
    d[t]  = sh ? a  : (here ? v : b);
    id[t] = sh ? ia : (here ? j : ib);
  }
  bool h0 = v < d[0];
  d[0]  = h0 ? v : d[0];
  id[0] = h0 ? j : id[0];
}

// ============ staging layout ============
// d_ws:   sq[NP] floats (64 KB)
// out record (512 B per point = 64 float2):
//   phase 1 (knn):   4 segments x 16 (d,id) float2 partials
//   phase 2 (merge): final 16 ids as ints [0..15]
//   phase 3 (mlp):   final 128 fp32 outputs overwrite the record

// ================= K0: squared norms -> ws =================
template<bool BF>
__device__ __forceinline__ void sq_body(const void* x, float* sqw) {
  int i = blockIdx.x * 256 + threadIdx.x;
  float acc = 0.f;
  if (BF) {
    const uint4* xr = (const uint4*)((const u16*)x + (size_t)i * FD);
#pragma unroll
    for (int u = 0; u < 8; ++u) {
      uint4 t = xr[u];
      float v[8] = {blo(t.x), bhi(t.x), blo(t.y), bhi(t.y),
                    blo(t.z), bhi(t.z), blo(t.w), bhi(t.w)};
#pragma unroll
      for (int j = 0; j < 8; ++j) acc = fmaf(v[j], v[j], acc);
    }
  } else {
    const float4* xr = (const float4*)((const float*)x + (size_t)i * FD);
#pragma unroll
    for (int u = 0; u < 16; ++u) {
      float4 t = xr[u];
      acc = fmaf(t.x, t.x, acc); acc = fmaf(t.y, t.y, acc);
      acc = fmaf(t.z, t.z, acc); acc = fmaf(t.w, t.w, acc);
    }
  }
  sqw[i] = acc;
}
__global__ __launch_bounds__(256) void sq_kernel(const void* x, float* sqw) {
  if (sniff_bf16(x)) sq_body<true>(x, sqw); else sq_body<false>(x, sqw);
}

// ======== K1: kNN partials. grid (256 row-blocks, 4 segs); 64 rows/block ========
// lane = row, wave = 1024-col sub-segment (wave-uniform j -> scalar xj/sq loads).
// d' = sqj - 2*dot (sqi dropped: row-constant, ordering-invariant).
// Candidate buffering: threshold test + LDS push per iter; batched insert16 at flush.
// Selection provably identical to direct insert (threshold is exact between flushes).
template<bool BF>
__device__ __forceinline__ void knn_body(const void* x, float* outf,
                                         const float* __restrict__ sqw) {
  __shared__ float2 part[16][4][16];       // 8 KB (16-row merge chunks)
  __shared__ float2 cbuf[4][CB + 1][64];   // 18 KB: [wave][slot][lane]; slot CB = dump

  int tid = threadIdx.x;
  int q = __builtin_amdgcn_readfirstlane(tid >> 6);   // wave id, provably uniform
  int r = tid & 63;
  int i = blockIdx.x * 64 + r;
  int seg0 = blockIdx.y * 4096;

  u32     xiw[32];   // bf16 path
  floatx2 xi2[32];   // fp32 path (pk pairs)
  if (BF) {
    const uint4* xip = (const uint4*)((const u16*)x + (size_t)i * FD);
#pragma unroll
    for (int u = 0; u < 8; ++u) {
      uint4 t = xip[u];
      xiw[4*u+0] = t.x; xiw[4*u+1] = t.y; xiw[4*u+2] = t.z; xiw[4*u+3] = t.w;
    }
  } else {
    const float4* xip = (const float4*)((const float*)x + (size_t)i * FD);
#pragma unroll
    for (int u = 0; u < 16; ++u) {
      float4 t = xip[u];
      floatx2 lo = {t.x, t.y}, hi = {t.z, t.w};
      xi2[2*u] = lo; xi2[2*u+1] = hi;
    }
  }

  float d16[16]; int i16[16];
#pragma unroll
  for (int t = 0; t < 16; ++t) { d16[t] = FLT_BIG; i16[t] = 0; }

  float2* myb = &cbuf[q][0][r];   // element e at myb[e*64]
  int cnt = 0;

  int jbase = seg0 + q * 1024;
  for (int jj = 0; jj < 1024; ++jj) {
    int j = jbase + jj;                                // wave-uniform
    float sqj = sqw[j];                                // uniform -> scalar load
    float dot;
    if (BF) {
      float a0 = 0.f, a1 = 0.f, a2 = 0.f, a3 = 0.f;
      const uint4* xjp = (const uint4*)((const u16*)x + (size_t)j * FD);
#pragma unroll
      for (int u = 0; u < 8; ++u) {
        uint4 t = xjp[u];
#ifdef HAVE_DOT2
        a0 = __builtin_amdgcn_fdot2_f32_bf16(asbf2(xiw[4*u+0]), asbf2(t.x), a0, false);
        a1 = __builtin_amdgcn_fdot2_f32_bf16(asbf2(xiw[4*u+1]), asbf2(t.y), a1, false);
        a2 = __builtin_amdgcn_fdot2_f32_bf16(asbf2(xiw[4*u+2]), asbf2(t.z), a2, false);
        a3 = __builtin_amdgcn_fdot2_f32_bf16(asbf2(xiw[4*u+3]), asbf2(t.w), a3, false);
#else
        a0 = fmaf(blo(xiw[4*u+0]), blo(t.x), a0); a1 = fmaf(bhi(xiw[4*u+0]), bhi(t.x), a1);
        a2 = fmaf(blo(xiw[4*u+1]), blo(t.y), a2); a3 = fmaf(bhi(xiw[4*u+1]), bhi(t.y), a3);
        a0 = fmaf(blo(xiw[4*u+2]), blo(t.z), a0); a1 = fmaf(bhi(xiw[4*u+2]), bhi(t.z), a1);
        a2 = fmaf(blo(xiw[4*u+3]), blo(t.w), a2); a3 = fmaf(bhi(xiw[4*u+3]), bhi(t.w), a3);
#endif
      }
      dot = (a0 + a1) + (a2 + a3);
    } else {
      floatx2 A01 = {0.f, 0.f}, A23 = {0.f, 0.f};
      const float4* xjp = (const float4*)((const float*)x + (size_t)j * FD);
#pragma unroll
      for (int u = 0; u < 16; ++u) {
        float4 t = xjp[u];
        floatx2 tl = {t.x, t.y}, th = {t.z, t.w};
        A01 = pkfma(xi2[2*u],   tl, A01);
        A23 = pkfma(xi2[2*u+1], th, A23);
      }
      dot = (A01.x + A01.y) + (A23.x + A23.y);   // same association as R7
    }
    float d = fmaf(-2.f, dot, sqj);
    if (j == i) d = FLT_BIG;                           // exclude self

    bool push = d < d16[15];                           // exact live threshold
    myb[(push ? cnt : CB) * 64] = make_float2(d, __int_as_float(j));
    cnt += push ? 1 : 0;
    if (__any(cnt == CB)) {                            // uniform branch
#pragma unroll
      for (int e = 0; e < CB; ++e) {
        float2 v = myb[e * 64];
        float dv = (e < cnt) ? v.x : FLT_BIG;
        if (dv < d16[15]) insert16(d16, i16, dv, __float_as_int(v.y));
      }
      cnt = 0;
    }
  }
  // drain remaining candidates
#pragma unroll
  for (int e = 0; e < CB; ++e) {
    float2 v = myb[e * 64];
    float dv = (e < cnt) ? v.x : FLT_BIG;
    if (dv < d16[15]) insert16(d16, i16, dv, __float_as_int(v.y));
  }

  // chunked cross-wave merge: 4 chunks of 16 rows through 8 KB LDS
  for (int c = 0; c < 4; ++c) {
    __syncthreads();
    if ((r >> 4) == c) {
      int rr = r & 15;
#pragma unroll
      for (int t = 0; t < 16; ++t)
        part[rr][q][t] = make_float2(d16[t], __int_as_float(i16[t]));
    }
    __syncthreads();
    if (tid < 16) {
      float f16d[16]; int f16i[16];
#pragma unroll
      for (int t = 0; t < 16; ++t) { f16d[t] = FLT_BIG; f16i[t] = 0; }
      for (int q2 = 0; q2 < 4; ++q2)        // wave-major = j-ascending: stable ties
        for (int t = 0; t < 16; ++t) {
          float2 v = part[tid][q2][t];
          if (v.x < f16d[15]) insert16(f16d, f16i, v.x, __float_as_int(v.y));
        }
      float2* op = (float2*)outf + (size_t)(blockIdx.x * 64 + c * 16 + tid) * 64
                   + blockIdx.y * 16;
#pragma unroll
      for (int t = 0; t < 16; ++t)
        op[t] = make_float2(f16d[t], __int_as_float(f16i[t]));
    }
  }
}
__global__ __launch_bounds__(256, 4) void knn_kernel(const void* x, float* outf,
                                                     const float* __restrict__ sqw) {
  if (sniff_bf16(x)) knn_body<true>(x, outf, sqw);
  else               knn_body<false>(x, outf, sqw);
}

// ======== K2: merge 4 segment partials -> final 16 ids (record ints [0..15]) ========
__global__ __launch_bounds__(256) void merge_kernel(float* outf) {
  int i = blockIdx.x * 256 + threadIdx.x;
  const float2* cp = (const float2*)outf + (size_t)i * 64;
  float d16[16]; int i16[16];
#pragma unroll
  for (int t = 0; t < 16; ++t) { d16[t] = FLT_BIG; i16[t] = 0; }
  for (int t = 0; t < 64; ++t) {          // seg-major = j-ascending: stable ties
    float2 v = cp[t];
    if (v.x < d16[15]) insert16(d16, i16, v.x, __float_as_int(v.y));
  }
  int* op = (int*)outf + (size_t)i * 128;
#pragma unroll
  for (int t = 0; t < 16; ++t) op[t] = i16[t];
}

// ================= K3: edge MLP + max aggregation (MFMA, bf16 compute) =================
// A-frag 16x16x32: lane holds A[m=l&15][k=(l>>4)*8+j].  C/D: col=l&15, row=(l>>4)*4+reg.
template<bool BF>
__device__ __forceinline__ void mlp_body(
    const void* x, const void* W1, const void* b1,
    const void* W2, const void* b2, float* outf,
    short* w1f, short* w2f, short (*hbuf)[2048]) {
  int tid = threadIdx.x;
  for (int s2 = tid; s2 < 4096; s2 += 256) {
    int which = s2 >> 11, t = s2 & 2047;
    int frag = t >> 6, lane = t & 63;
    int nt = frag >> 2, kk = frag & 3;
    int n  = nt * 16 + (lane & 15);
    int kb = kk * 32 + ((lane >> 4) * 8);
    short8 v;
    if (BF) {
      const u16* W = (const u16*)(which ? W2 : W1);
#pragma unroll
      for (int j = 0; j < 8; ++j) v[j] = (short)W[(size_t)(kb + j) * 128 + n];
    } else {
      const float* W = (const float*)(which ? W2 : W1);
#pragma unroll
      for (int j = 0; j < 8; ++j) v[j] = (short)f2bf(W[(size_t)(kb + j) * 128 + n]);
    }
    *(short8*)((which ? w2f : w1f) + t * 8) = v;
  }
  __syncthreads();

  int l = tid & 63, w = tid >> 6;
  int q = l >> 4, c = l & 15;
  short* hb = hbuf[w];

  float b1v[8], b2v[8];
#pragma unroll
  for (int nt = 0; nt < 8; ++nt) {
    b1v[nt] = BF ? bf2f(((const u16*)b1)[nt * 16 + c]) : ((const float*)b1)[nt * 16 + c];
    b2v[nt] = BF ? bf2f(((const u16*)b2)[nt * 16 + c]) : ((const float*)b2)[nt * 16 + c];
  }

  int wid = blockIdx.x * 4 + w;
  for (int p = wid; p < NP; p += 1024) {
    int nb = ((const int*)outf)[(size_t)p * 128 + c] & (NP - 1);
    short8 a1[4];
    if (BF) {
      const short* xp  = (const short*)x + (size_t)p  * FD;
      const short* xnp = (const short*)x + (size_t)nb * FD;
      a1[0] = *(const short8*)(xp + q * 8);
      a1[1] = *(const short8*)(xp + 32 + q * 8);
#pragma unroll
      for (int kk = 2; kk < 4; ++kk) {
        int kb = (kk - 2) * 32 + q * 8;
        short8 xi8 = *(const short8*)(xp + kb);
        short8 xj8 = *(const short8*)(xnp + kb);
        short8 dfr;
#pragma unroll
        for (int j = 0; j < 8; ++j)
          dfr[j] = (short)f2bf(bf2f((u16)xj8[j]) - bf2f((u16)xi8[j]));
        a1[kk] = dfr;
      }
    } else {
      const float* xp  = (const float*)x + (size_t)p  * FD;
      const float* xnp = (const float*)x + (size_t)nb * FD;
#pragma unroll
      for (int j = 0; j < 8; ++j) {
        float xi0 = xp[q * 8 + j], xi1 = xp[32 + q * 8 + j];
        float xj0 = xnp[q * 8 + j], xj1 = xnp[32 + q * 8 + j];
        a1[0][j] = (short)f2bf(xi0);
        a1[1][j] = (short)f2bf(xi1);
        a1[2][j] = (short)f2bf(xj0 - xi0);
        a1[3][j] = (short)f2bf(xj1 - xi1);
      }
    }

#pragma unroll
    for (int nt = 0; nt < 8; ++nt) {
      floatx4 acc = {0.f, 0.f, 0.f, 0.f};
#pragma unroll
      for (int kk = 0; kk < 4; ++kk) {
        short8 b = *(const short8*)(w1f + ((nt * 4 + kk) * 64 + l) * 8);
        acc = __builtin_amdgcn_mfma_f32_16x16x32_bf16(a1[kk], b, acc, 0, 0, 0);
      }
#pragma unroll
      for (int r = 0; r < 4; ++r) {
        float v = acc[r] + b1v[nt];
        v = v > 0.f ? v : 0.f;
        int row  = q * 4 + r;
        int hcol = nt * 16 + c;
        int eidx = ((hcol >> 5) * 64 + ((hcol >> 3) & 3) * 16 + row) * 8 + (hcol & 7);
        hb[eidx] = (short)f2bf(v);
      }
    }

    short8 a2[4];
#pragma unroll
    for (int kk = 0; kk < 4; ++kk)
      a2[kk] = *(const short8*)(hb + (kk * 64 + l) * 8);
#pragma unroll
    for (int nt = 0; nt < 8; ++nt) {
      floatx4 acc = {0.f, 0.f, 0.f, 0.f};
#pragma unroll
      for (int kk = 0; kk < 4; ++kk) {
        short8 b = *(const short8*)(w2f + ((nt * 4 + kk) * 64 + l) * 8);
        acc = __builtin_amdgcn_mfma_f32_16x16x32_bf16(a2[kk], b, acc, 0, 0, 0);
      }
      float m = fmaxf(fmaxf(acc[0], acc[1]), fmaxf(acc[2], acc[3])) + b2v[nt];
      m = fmaxf(m, __shfl_xor(m, 16, 64));
      m = fmaxf(m, __shfl_xor(m, 32, 64));
      if (q == 0) outf[(size_t)p * 128 + nt * 16 + c] = m;
    }
  }
}
__global__ __launch_bounds__(256) void mlp_kernel(
    const void* x, const void* W1, const void* b1,
    const void* W2, const void* b2, float* outf) {
  __shared__ short w1f[16384];
  __shared__ short w2f[16384];
  __shared__ short hbuf[4][2048];
  if (sniff_bf16(x)) mlp_body<true>(x, W1, b1, W2, b2, outf, w1f, w2f, hbuf);
  else               mlp_body<false>(x, W1, b1, W2, b2, outf, w1f, w2f, hbuf);
}

extern "C" void kernel_launch(void* const* d_in, const int* in_sizes, int n_in,
                              void* d_out, int out_size, void* d_ws, size_t ws_size,
                              hipStream_t stream) {
  const void* x  = d_in[0];
  const void* W1 = d_in[1];
  const void* b1 = d_in[2];
  const void* W2 = d_in[3];
  const void* b2 = d_in[4];
  float* outf = (float*)d_out;
  float* sqw  = (float*)d_ws;          // NP floats = 64 KB

  sq_kernel   <<<dim3(NP / 256),   dim3(256), 0, stream>>>(x, sqw);
  knn_kernel  <<<dim3(NP / 64, 4), dim3(256), 0, stream>>>(x, outf, sqw);
  merge_kernel<<<dim3(NP / 256),   dim3(256), 0, stream>>>(outf);
  mlp_kernel  <<<dim3(256),        dim3(256), 0, stream>>>(x, W1, b1, W2, b2, outf);
}

// Round 10
// 933.359 us; speedup vs baseline: 1.5674x; 1.4691x over previous
//
#include <hip/hip_runtime.h>
#include <hip/hip_bf16.h>

typedef unsigned short u16;
typedef unsigned int u32;
typedef __attribute__((ext_vector_type(8))) short short8;
typedef __attribute__((ext_vector_type(4))) float floatx4;
typedef __attribute__((ext_vector_type(2))) float floatx2;

#define NP 16384
#define FD 64
#define FLT_BIG 3.0e38f
#define CB 8                      // candidate buffer depth per lane

#if defined(__has_builtin)
#if __has_builtin(__builtin_amdgcn_fdot2_f32_bf16)
#define HAVE_DOT2 1
#endif
#endif

__device__ __forceinline__ float blo(u32 u) {
  u32 v = u << 16; float f; __builtin_memcpy(&f, &v, 4); return f;
}
__device__ __forceinline__ float bhi(u32 u) {
  u32 v = u & 0xffff0000u; float f; __builtin_memcpy(&f, &v, 4); return f;
}
__device__ __forceinline__ float bf2f(u16 u) {
  u32 v = ((u32)u) << 16; float f; __builtin_memcpy(&f, &v, 4); return f;
}
__device__ __forceinline__ u16 f2bf(float f) {
  u32 u; __builtin_memcpy(&u, &f, 4);
  u += 0x7fffu + ((u >> 16) & 1u);
  return (u16)(u >> 16);
}

#ifdef HAVE_DOT2
typedef __attribute__((ext_vector_type(2))) __bf16 bf16x2;
__device__ __forceinline__ bf16x2 asbf2(u32 u) {
  bf16x2 r; __builtin_memcpy(&r, &u, 4); return r;
}
#endif

__device__ __forceinline__ floatx2 pkfma(floatx2 a, floatx2 b, floatx2 c) {
#if defined(__has_builtin) && __has_builtin(__builtin_elementwise_fma)
  return __builtin_elementwise_fma(a, b, c);   // v_pk_fma_f32
#else
  floatx2 r; r.x = fmaf(a.x, b.x, c.x); r.y = fmaf(a.y, b.y, c.y); return r;
#endif
}

// runtime input-dtype sniff (confirmed fp32 in R4/R5; kept for safety)
__device__ __forceinline__ bool sniff_bf16(const void* xg) {
  const u16* p = (const u16*)xg;
  int bad = 0;
#pragma unroll
  for (int t = 0; t < 32; ++t) {
    int e = (p[2 * t] >> 7) & 0xFF;
    bad += (e < 90 || e > 132) ? 1 : 0;
  }
  return bad <= 3;
}

// insert v (known < d[15]) into ascending-sorted 16-array, stable (earlier wins ties)
__device__ __forceinline__ void insert16(float (&d)[16], int (&id)[16], float v, int j) {
#pragma unroll
  for (int t = 15; t >= 1; --t) {
    float a = d[t-1], b = d[t];
    int   ia = id[t-1], ib = id[t];
    bool sh   = v < a;
    bool here = v < b;
    d[t]  = sh ? a  : (here ? v : b);
    id[t] = sh ? ia : (here ? j : ib);
  }
  bool h0 = v < d[0];
  d[0]  = h0 ? v : d[0];
  id[0] = h0 ? j : id[0];
}

// ============ staging layout ============
// d_ws:   sq[NP] floats (64 KB)
// out record (512 B per point = 64 float2):
//   phase 1 (knn):   4 segments x 16 (d,id) float2 partials
//   phase 2 (merge): final 16 ids as ints [0..15]
//   phase 3 (mlp):   final 128 fp32 outputs overwrite the record

// ================= K0: squared norms -> ws =================
template<bool BF>
__device__ __forceinline__ void sq_body(const void* x, float* sqw) {
  int i = blockIdx.x * 256 + threadIdx.x;
  float acc = 0.f;
  if (BF) {
    const uint4* xr = (const uint4*)((const u16*)x + (size_t)i * FD);
#pragma unroll
    for (int u = 0; u < 8; ++u) {
      uint4 t = xr[u];
      float v[8] = {blo(t.x), bhi(t.x), blo(t.y), bhi(t.y),
                    blo(t.z), bhi(t.z), blo(t.w), bhi(t.w)};
#pragma unroll
      for (int j = 0; j < 8; ++j) acc = fmaf(v[j], v[j], acc);
    }
  } else {
    const float4* xr = (const float4*)((const float*)x + (size_t)i * FD);
#pragma unroll
    for (int u = 0; u < 16; ++u) {
      float4 t = xr[u];
      acc = fmaf(t.x, t.x, acc); acc = fmaf(t.y, t.y, acc);
      acc = fmaf(t.z, t.z, acc); acc = fmaf(t.w, t.w, acc);
    }
  }
  sqw[i] = acc;
}
__global__ __launch_bounds__(256) void sq_kernel(const void* x, float* sqw) {
  if (sniff_bf16(x)) sq_body<true>(x, sqw); else sq_body<false>(x, sqw);
}

// ======== K1: kNN partials. grid (256 row-blocks, 4 segs); 64 rows/block ========
// lane = row, wave = 1024-col sub-segment (wave-uniform j -> scalar xj/sq loads).
// d' = sqj - 2*dot (sqi dropped: row-constant, ordering-invariant).
// Candidate buffering: threshold test + LDS push per iter; batched insert16 at flush.
// LDS: single 18 KB arena, UNION of cbuf (loop phase) and part (merge phase);
// allocated ONCE at kernel scope (template-body __shared__ double-allocates!).
template<bool BF>
__device__ __forceinline__ void knn_body(const void* x, float* outf,
                                         const float* __restrict__ sqw,
                                         float2* smem) {
  // loop phase:  cbuf[wave][slot][lane], slot CB = dump slot
  float2 (*cbuf)[CB + 1][64] = (float2 (*)[CB + 1][64])smem;
  // merge phase: part[row16][wave][16]  (overlays cbuf; safe: see sync below)
  float2 (*part)[4][16] = (float2 (*)[4][16])smem;

  int tid = threadIdx.x;
  int q = __builtin_amdgcn_readfirstlane(tid >> 6);   // wave id, provably uniform
  int r = tid & 63;
  int i = blockIdx.x * 64 + r;
  int seg0 = blockIdx.y * 4096;

  u32     xiw[32];   // bf16 path
  floatx2 xi2[32];   // fp32 path (pk pairs)
  if (BF) {
    const uint4* xip = (const uint4*)((const u16*)x + (size_t)i * FD);
#pragma unroll
    for (int u = 0; u < 8; ++u) {
      uint4 t = xip[u];
      xiw[4*u+0] = t.x; xiw[4*u+1] = t.y; xiw[4*u+2] = t.z; xiw[4*u+3] = t.w;
    }
  } else {
    const float4* xip = (const float4*)((const float*)x + (size_t)i * FD);
#pragma unroll
    for (int u = 0; u < 16; ++u) {
      float4 t = xip[u];
      floatx2 lo = {t.x, t.y}, hi = {t.z, t.w};
      xi2[2*u] = lo; xi2[2*u+1] = hi;
    }
  }

  float d16[16]; int i16[16];
#pragma unroll
  for (int t = 0; t < 16; ++t) { d16[t] = FLT_BIG; i16[t] = 0; }

  float2* myb = &cbuf[q][0][r];   // element e at myb[e*64]
  int cnt = 0;

  int jbase = seg0 + q * 1024;
  for (int jj = 0; jj < 1024; ++jj) {
    int j = jbase + jj;                                // wave-uniform
    float sqj = sqw[j];                                // uniform -> scalar load
    float dot;
    if (BF) {
      float a0 = 0.f, a1 = 0.f, a2 = 0.f, a3 = 0.f;
      const uint4* xjp = (const uint4*)((const u16*)x + (size_t)j * FD);
#pragma unroll
      for (int u = 0; u < 8; ++u) {
        uint4 t = xjp[u];
#ifdef HAVE_DOT2
        a0 = __builtin_amdgcn_fdot2_f32_bf16(asbf2(xiw[4*u+0]), asbf2(t.x), a0, false);
        a1 = __builtin_amdgcn_fdot2_f32_bf16(asbf2(xiw[4*u+1]), asbf2(t.y), a1, false);
        a2 = __builtin_amdgcn_fdot2_f32_bf16(asbf2(xiw[4*u+2]), asbf2(t.z), a2, false);
        a3 = __builtin_amdgcn_fdot2_f32_bf16(asbf2(xiw[4*u+3]), asbf2(t.w), a3, false);
#else
        a0 = fmaf(blo(xiw[4*u+0]), blo(t.x), a0); a1 = fmaf(bhi(xiw[4*u+0]), bhi(t.x), a1);
        a2 = fmaf(blo(xiw[4*u+1]), blo(t.y), a2); a3 = fmaf(bhi(xiw[4*u+1]), bhi(t.y), a3);
        a0 = fmaf(blo(xiw[4*u+2]), blo(t.z), a0); a1 = fmaf(bhi(xiw[4*u+2]), bhi(t.z), a1);
        a2 = fmaf(blo(xiw[4*u+3]), blo(t.w), a2); a3 = fmaf(bhi(xiw[4*u+3]), bhi(t.w), a3);
#endif
      }
      dot = (a0 + a1) + (a2 + a3);
    } else {
      floatx2 A01 = {0.f, 0.f}, A23 = {0.f, 0.f};
      const float4* xjp = (const float4*)((const float*)x + (size_t)j * FD);
#pragma unroll
      for (int u = 0; u < 16; ++u) {
        float4 t = xjp[u];
        floatx2 tl = {t.x, t.y}, th = {t.z, t.w};
        A01 = pkfma(xi2[2*u],   tl, A01);
        A23 = pkfma(xi2[2*u+1], th, A23);
      }
      dot = (A01.x + A01.y) + (A23.x + A23.y);   // same association as R7
    }
    float d = fmaf(-2.f, dot, sqj);
    if (j == i) d = FLT_BIG;                           // exclude self

    bool push = d < d16[15];                           // exact live threshold
    myb[(push ? cnt : CB) * 64] = make_float2(d, __int_as_float(j));
    cnt += push ? 1 : 0;
    if (__any(cnt == CB)) {                            // uniform branch
#pragma unroll
      for (int e = 0; e < CB; ++e) {
        float2 v = myb[e * 64];
        float dv = (e < cnt) ? v.x : FLT_BIG;
        if (dv < d16[15]) insert16(d16, i16, dv, __float_as_int(v.y));
      }
      cnt = 0;
    }
  }
  // drain remaining candidates (before any part write — cbuf dies here)
#pragma unroll
  for (int e = 0; e < CB; ++e) {
    float2 v = myb[e * 64];
    float dv = (e < cnt) ? v.x : FLT_BIG;
    if (dv < d16[15]) insert16(d16, i16, dv, __float_as_int(v.y));
  }

  // chunked cross-wave merge: 4 chunks of 16 rows through the (re-used) LDS arena.
  // First __syncthreads guarantees every wave has drained cbuf before overlay.
  for (int c = 0; c < 4; ++c) {
    __syncthreads();
    if ((r >> 4) == c) {
      int rr = r & 15;
#pragma unroll
      for (int t = 0; t < 16; ++t)
        part[rr][q][t] = make_float2(d16[t], __int_as_float(i16[t]));
    }
    __syncthreads();
    if (tid < 16) {
      float f16d[16]; int f16i[16];
#pragma unroll
      for (int t = 0; t < 16; ++t) { f16d[t] = FLT_BIG; f16i[t] = 0; }
      for (int q2 = 0; q2 < 4; ++q2)        // wave-major = j-ascending: stable ties
        for (int t = 0; t < 16; ++t) {
          float2 v = part[tid][q2][t];
          if (v.x < f16d[15]) insert16(f16d, f16i, v.x, __float_as_int(v.y));
        }
      float2* op = (float2*)outf + (size_t)(blockIdx.x * 64 + c * 16 + tid) * 64
                   + blockIdx.y * 16;
#pragma unroll
      for (int t = 0; t < 16; ++t)
        op[t] = make_float2(f16d[t], __int_as_float(f16i[t]));
    }
  }
}
__global__ __launch_bounds__(256, 4) void knn_kernel(const void* x, float* outf,
                                                     const float* __restrict__ sqw) {
  __shared__ float2 smem[4 * (CB + 1) * 64];   // 18432 B, single allocation
  if (sniff_bf16(x)) knn_body<true>(x, outf, sqw, smem);
  else               knn_body<false>(x, outf, sqw, smem);
}

// ======== K2: merge 4 segment partials -> final 16 ids (record ints [0..15]) ========
__global__ __launch_bounds__(256) void merge_kernel(float* outf) {
  int i = blockIdx.x * 256 + threadIdx.x;
  const float2* cp = (const float2*)outf + (size_t)i * 64;
  float d16[16]; int i16[16];
#pragma unroll
  for (int t = 0; t < 16; ++t) { d16[t] = FLT_BIG; i16[t] = 0; }
  for (int t = 0; t < 64; ++t) {          // seg-major = j-ascending: stable ties
    float2 v = cp[t];
    if (v.x < d16[15]) insert16(d16, i16, v.x, __float_as_int(v.y));
  }
  int* op = (int*)outf + (size_t)i * 128;
#pragma unroll
  for (int t = 0; t < 16; ++t) op[t] = i16[t];
}

// ================= K3: edge MLP + max aggregation (MFMA, bf16 compute) =================
// A-frag 16x16x32: lane holds A[m=l&15][k=(l>>4)*8+j].  C/D: col=l&15, row=(l>>4)*4+reg.
template<bool BF>
__device__ __forceinline__ void mlp_body(
    const void* x, const void* W1, const void* b1,
    const void* W2, const void* b2, float* outf,
    short* w1f, short* w2f, short (*hbuf)[2048]) {
  int tid = threadIdx.x;
  for (int s2 = tid; s2 < 4096; s2 += 256) {
    int which = s2 >> 11, t = s2 & 2047;
    int frag = t >> 6, lane = t & 63;
    int nt = frag >> 2, kk = frag & 3;
    int n  = nt * 16 + (lane & 15);
    int kb = kk * 32 + ((lane >> 4) * 8);
    short8 v;
    if (BF) {
      const u16* W = (const u16*)(which ? W2 : W1);
#pragma unroll
      for (int j = 0; j < 8; ++j) v[j] = (short)W[(size_t)(kb + j) * 128 + n];
    } else {
      const float* W = (const float*)(which ? W2 : W1);
#pragma unroll
      for (int j = 0; j < 8; ++j) v[j] = (short)f2bf(W[(size_t)(kb + j) * 128 + n]);
    }
    *(short8*)((which ? w2f : w1f) + t * 8) = v;
  }
  __syncthreads();

  int l = tid & 63, w = tid >> 6;
  int q = l >> 4, c = l & 15;
  short* hb = hbuf[w];

  float b1v[8], b2v[8];
#pragma unroll
  for (int nt = 0; nt < 8; ++nt) {
    b1v[nt] = BF ? bf2f(((const u16*)b1)[nt * 16 + c]) : ((const float*)b1)[nt * 16 + c];
    b2v[nt] = BF ? bf2f(((const u16*)b2)[nt * 16 + c]) : ((const float*)b2)[nt * 16 + c];
  }

  int wid = blockIdx.x * 4 + w;
  for (int p = wid; p < NP; p += 1024) {
    int nb = ((const int*)outf)[(size_t)p * 128 + c] & (NP - 1);
    short8 a1[4];
    if (BF) {
      const short* xp  = (const short*)x + (size_t)p  * FD;
      const short* xnp = (const short*)x + (size_t)nb * FD;
      a1[0] = *(const short8*)(xp + q * 8);
      a1[1] = *(const short8*)(xp + 32 + q * 8);
#pragma unroll
      for (int kk = 2; kk < 4; ++kk) {
        int kb = (kk - 2) * 32 + q * 8;
        short8 xi8 = *(const short8*)(xp + kb);
        short8 xj8 = *(const short8*)(xnp + kb);
        short8 dfr;
#pragma unroll
        for (int j = 0; j < 8; ++j)
          dfr[j] = (short)f2bf(bf2f((u16)xj8[j]) - bf2f((u16)xi8[j]));
        a1[kk] = dfr;
      }
    } else {
      const float* xp  = (const float*)x + (size_t)p  * FD;
      const float* xnp = (const float*)x + (size_t)nb * FD;
#pragma unroll
      for (int j = 0; j < 8; ++j) {
        float xi0 = xp[q * 8 + j], xi1 = xp[32 + q * 8 + j];
        float xj0 = xnp[q * 8 + j], xj1 = xnp[32 + q * 8 + j];
        a1[0][j] = (short)f2bf(xi0);
        a1[1][j] = (short)f2bf(xi1);
        a1[2][j] = (short)f2bf(xj0 - xi0);
        a1[3][j] = (short)f2bf(xj1 - xi1);
      }
    }

#pragma unroll
    for (int nt = 0; nt < 8; ++nt) {
      floatx4 acc = {0.f, 0.f, 0.f, 0.f};
#pragma unroll
      for (int kk = 0; kk < 4; ++kk) {
        short8 b = *(const short8*)(w1f + ((nt * 4 + kk) * 64 + l) * 8);
        acc = __builtin_amdgcn_mfma_f32_16x16x32_bf16(a1[kk], b, acc, 0, 0, 0);
      }
#pragma unroll
      for (int r = 0; r < 4; ++r) {
        float v = acc[r] + b1v[nt];
        v = v > 0.f ? v : 0.f;
        int row  = q * 4 + r;
        int hcol = nt * 16 + c;
        int eidx = ((hcol >> 5) * 64 + ((hcol >> 3) & 3) * 16 + row) * 8 + (hcol & 7);
        hb[eidx] = (short)f2bf(v);
      }
    }

    short8 a2[4];
#pragma unroll
    for (int kk = 0; kk < 4; ++kk)
      a2[kk] = *(const short8*)(hb + (kk * 64 + l) * 8);
#pragma unroll
    for (int nt = 0; nt < 8; ++nt) {
      floatx4 acc = {0.f, 0.f, 0.f, 0.f};
#pragma unroll
      for (int kk = 0; kk < 4; ++kk) {
        short8 b = *(const short8*)(w2f + ((nt * 4 + kk) * 64 + l) * 8);
        acc = __builtin_amdgcn_mfma_f32_16x16x32_bf16(a2[kk], b, acc, 0, 0, 0);
      }
      float m = fmaxf(fmaxf(acc[0], acc[1]), fmaxf(acc[2], acc[3])) + b2v[nt];
      m = fmaxf(m, __shfl_xor(m, 16, 64));
      m = fmaxf(m, __shfl_xor(m, 32, 64));
      if (q == 0) outf[(size_t)p * 128 + nt * 16 + c] = m;
    }
  }
}
__global__ __launch_bounds__(256) void mlp_kernel(
    const void* x, const void* W1, const void* b1,
    const void* W2, const void* b2, float* outf) {
  __shared__ short w1f[16384];
  __shared__ short w2f[16384];
  __shared__ short hbuf[4][2048];
  if (sniff_bf16(x)) mlp_body<true>(x, W1, b1, W2, b2, outf, w1f, w2f, hbuf);
  else               mlp_body<false>(x, W1, b1, W2, b2, outf, w1f, w2f, hbuf);
}

extern "C" void kernel_launch(void* const* d_in, const int* in_sizes, int n_in,
                              void* d_out, int out_size, void* d_ws, size_t ws_size,
                              hipStream_t stream) {
  const void* x  = d_in[0];
  const void* W1 = d_in[1];
  const void* b1 = d_in[2];
  const void* W2 = d_in[3];
  const void* b2 = d_in[4];
  float* outf = (float*)d_out;
  float* sqw  = (float*)d_ws;          // NP floats = 64 KB

  sq_kernel   <<<dim3(NP / 256),   dim3(256), 0, stream>>>(x, sqw);
  knn_kernel  <<<dim3(NP / 64, 4), dim3(256), 0, stream>>>(x, outf, sqw);
  merge_kernel<<<dim3(NP / 256),   dim3(256), 0, stream>>>(outf);
  mlp_kernel  <<<dim3(256),        dim3(256), 0, stream>>>(x, W1, b1, W2, b2, outf);
}